// Round 15
// baseline (227.139 us; speedup 1.0000x reference)
//
#include <hip/hip_runtime.h>
#include <hip/hip_fp16.h>

#define HEADS 8
#define HID 128
#define DIN 64
#define DOUT 64
#define NBLK 512      // blocks for hist/scatter passes
#define BSH 8         // bucket shift: bucket = dst >> 8
#define BS 256        // nodes per bucket
#define MAXNB 512     // LDS capacity (NB = ceil(50000/256) = 196)

typedef _Float16 f16x2 __attribute__((ext_vector_type(2)));
union U8 { uint4 u4[2]; f16x2 h[8]; };
union X8 { uint4 u4[8]; f16x2 h[32]; };

__device__ __forceinline__ int h2i(f16x2 h) { union { f16x2 h; int i; } u; u.h = h; return u.i; }
__device__ __forceinline__ f16x2 i2h(int i) { union { f16x2 h; int i; } u; u.i = i; return u.h; }
__device__ __forceinline__ _Float16 us2h(unsigned short v) { union { unsigned short u; _Float16 h; } u; u.u = v; return u.h; }

// decode 16 fp8(e4m3) -> 8 x f16x2
__device__ __forceinline__ void cvt16(const uint4 v, f16x2* o) {
#if __has_builtin(__builtin_amdgcn_cvt_scalef32_pk_f16_fp8)
    o[0] = __builtin_amdgcn_cvt_scalef32_pk_f16_fp8(v.x, 1.0f, false);
    o[1] = __builtin_amdgcn_cvt_scalef32_pk_f16_fp8(v.x, 1.0f, true);
    o[2] = __builtin_amdgcn_cvt_scalef32_pk_f16_fp8(v.y, 1.0f, false);
    o[3] = __builtin_amdgcn_cvt_scalef32_pk_f16_fp8(v.y, 1.0f, true);
    o[4] = __builtin_amdgcn_cvt_scalef32_pk_f16_fp8(v.z, 1.0f, false);
    o[5] = __builtin_amdgcn_cvt_scalef32_pk_f16_fp8(v.z, 1.0f, true);
    o[6] = __builtin_amdgcn_cvt_scalef32_pk_f16_fp8(v.w, 1.0f, false);
    o[7] = __builtin_amdgcn_cvt_scalef32_pk_f16_fp8(v.w, 1.0f, true);
#else
    const f16x2 s256 = (f16x2){(_Float16)256.f, (_Float16)256.f};
    const unsigned* uu = &v.x;
#pragma unroll
    for (int j = 0; j < 4; ++j) {
        unsigned u = uu[j];
        unsigned plo = u & 0xFFFFu, phi = u >> 16;
        unsigned flo = ((plo & 0x80u) << 8) | ((plo & 0x7Fu) << 7)
                     | ((plo & 0x8000u) << 16) | ((plo & 0x7F00u) << 15);
        unsigned fhi = ((phi & 0x80u) << 8) | ((phi & 0x7Fu) << 7)
                     | ((phi & 0x8000u) << 16) | ((phi & 0x7F00u) << 15);
        o[2*j]   = i2h((int)flo) * s256;   // exact: fp8 bits as f16, exponent fixed by *2^8
        o[2*j+1] = i2h((int)fhi) * s256;
    }
#endif
}

__device__ __forceinline__ unsigned enc_fp8(float a) {
    float c = fminf(fmaxf(a, -448.f), 448.f);
    unsigned short hb = __half_as_ushort(__float2half(c));
    unsigned s = ((unsigned)hb >> 8) & 0x80u;
    unsigned lsb = (hb >> 7) & 1u;
    unsigned hr = (unsigned)hb + 0x3Fu + lsb;      // RNE at bit 7
    int e = (int)((hr >> 10) & 0x1Fu);
    if (e <= 8) {                                   // |c| < ~2^-6: subnormal fp8
        int m8 = (int)rintf(fabsf(c) * 512.f);
        if (m8 >= 8) return s | (1u << 3);
        return s | (unsigned)m8;
    }
    unsigned m3 = (hr >> 7) & 7u;
    int ef = e - 8;
    if (ef > 15) { ef = 15; m3 = 7u; }
    return s | ((unsigned)ef << 3) | m3;
}

__device__ __forceinline__ unsigned char to_fp8(float a) {
#if __has_builtin(__builtin_amdgcn_cvt_pk_fp8_f32)
    int v = __builtin_amdgcn_cvt_pk_fp8_f32(a, a, 0, false);
    return (unsigned char)(v & 0xFF);
#else
    return (unsigned char)enc_fp8(a);
#endif
}

// ---------------- A1: per-(block,bucket) histogram (bucket-major output) ----------------
__global__ void k_hist(const int* __restrict__ ei, int* __restrict__ h, int E, int NB) {
    __shared__ int hist[MAXNB];
    int i = blockIdx.x, t = threadIdx.x;
    for (int b = t; b < NB; b += 256) hist[b] = 0;
    __syncthreads();
    int chunk = (E + NBLK - 1) / NBLK;
    int e0 = i * chunk, e1 = min(E, e0 + chunk);
    for (int e = e0 + t; e < e1; e += 256) {
        int d = ei[E + e];
        atomicAdd(&hist[d >> BSH], 1);
    }
    __syncthreads();
    for (int b = t; b < NB; b += 256) h[b * NBLK + i] = hist[b];
}

// ---------------- A2a: parallel per-bucket column scan (coalesced) ----------------
__global__ void k_scancol(int* __restrict__ h, int* __restrict__ Btot, int NB) {
    __shared__ int s[256];
    int b = blockIdx.x, t = threadIdx.x;
    int* col = h + (size_t)b * NBLK;
    int v0 = col[2 * t], v1 = col[2 * t + 1];
    int pair = v0 + v1;
    s[t] = pair;
    __syncthreads();
    for (int off = 1; off < 256; off <<= 1) {
        int u = (t >= off) ? s[t - off] : 0;
        __syncthreads();
        s[t] += u;
        __syncthreads();
    }
    int excl = s[t] - pair;
    col[2 * t] = excl;
    col[2 * t + 1] = excl + v0;
    if (t == 255) Btot[b] = s[255];
}

// ---------------- A2b: bucket-level scan ----------------
__global__ void k_scanbuck(const int* __restrict__ Btot, int* __restrict__ Boff,
                           int* __restrict__ rowptr, int E, int N, int NB) {
    __shared__ int s[256];
    int t = threadIdx.x;
    int v = (t < NB) ? Btot[t] : 0;
    s[t] = v;
    __syncthreads();
    for (int off = 1; off < 256; off <<= 1) {
        int u = (t >= off) ? s[t - off] : 0;
        __syncthreads();
        s[t] += u;
        __syncthreads();
    }
    if (t < NB) Boff[t] = s[t] - v;
    if (t == 0) { Boff[NB] = E; rowptr[N] = E + N; }
}

// ---------------- A3: scatter records into bucket-sorted staging ----------------
__global__ void k_scatter(const int* __restrict__ ei, const float* __restrict__ ew,
                          const int* __restrict__ h, const int* __restrict__ Boff,
                          int2* __restrict__ barr, int E, int NB) {
    __shared__ int base[MAXNB];
    int i = blockIdx.x, t = threadIdx.x;
    for (int b = t; b < NB; b += 256) base[b] = h[b * NBLK + i] + Boff[b];
    __syncthreads();
    int chunk = (E + NBLK - 1) / NBLK;
    int e0 = i * chunk, e1 = min(E, e0 + chunk);
    for (int e = e0 + t; e < e1; e += 256) {
        int s = ei[e], d = ei[E + e];
        float w = ew[e];
        int slot = atomicAdd(&base[d >> BSH], 1);   // LDS atomic; disjoint ranges
        barr[slot] = make_int2(((d & (BS - 1)) << 16) | s, __float_as_int(w));
    }
}

// ---------------- B: bucket -> exact CSR; 512 threads for latency hiding ----------------
__global__ __launch_bounds__(512) void k_csr(
        const int2* __restrict__ barr, const int* __restrict__ Boff,
        int* __restrict__ rowptr, unsigned* __restrict__ csrw, int N, int NB) {
    __shared__ int cnt[BS];
    __shared__ int wfix[BS];
    __shared__ int off[BS];
    __shared__ int fill[BS];
    int b = blockIdx.x, t = threadIdx.x;
    int n0 = b << BSH;
    int nodes = min(BS, N - n0);
    if (t < BS) { cnt[t] = 0; wfix[t] = 0; }
    __syncthreads();
    int j0 = Boff[b], j1 = Boff[b + 1];
    for (int j = j0 + t; j < j1; j += 512) {
        int2 rec = barr[j];
        int dl = rec.x >> 16;
        atomicAdd(&cnt[dl], 1);
        atomicAdd(&wfix[dl], (int)(__int_as_float(rec.y) * 16777216.0f));  // 2^24 fixed-point
    }
    __syncthreads();
    int v = 0;
    if (t < BS) {
        v = (t < nodes) ? cnt[t] + 1 : 0;   // +1 self loop
        off[t] = v;
    }
    __syncthreads();
    for (int o = 1; o < BS; o <<= 1) {
        int u = 0;
        if (t < BS && t >= o) u = off[t - o];
        __syncthreads();
        if (t < BS) off[t] += u;
        __syncthreads();
    }
    int rowBase = j0 + n0;
    if (t < nodes) {
        int rs = rowBase + off[t] - v;
        rowptr[n0 + t] = rs;
        int c = cnt[t];
        float mean = (c > 0) ? ((float)wfix[t] * (1.f / 16777216.f)) / (float)c : 0.f;
        csrw[rs + c] = (unsigned)(n0 + t)
                     | ((unsigned)__half_as_ushort(__float2half(mean)) << 16);  // self-loop
        fill[t] = rs;
    }
    __syncthreads();
    for (int j = j0 + t; j < j1; j += 512) {
        int2 rec = barr[j];
        int dl = rec.x >> 16;
        int pos = atomicAdd(&fill[dl], 1);
        unsigned wb = (unsigned)__half_as_ushort(__float2half(__int_as_float(rec.y)));
        csrw[pos] = (unsigned)(rec.x & 0xFFFF) | (wb << 16);
    }
}

// ---------------- x f32 -> f16 (8 values/thread) ----------------
__global__ void k_x16(const float* __restrict__ x, __half* __restrict__ x16, int total8) {
    int i = blockIdx.x * blockDim.x + threadIdx.x;
    if (i >= total8) return;
    const float4* p = (const float4*)(x + (size_t)i * 8);
    float4 a = p[0], b = p[1];
    union { __half h[8]; uint4 u; } o;
    o.h[0] = __float2half(a.x); o.h[1] = __float2half(a.y);
    o.h[2] = __float2half(a.z); o.h[3] = __float2half(a.w);
    o.h[4] = __float2half(b.x); o.h[5] = __float2half(b.y);
    o.h[6] = __float2half(b.z); o.h[7] = __float2half(b.w);
    ((uint4*)x16)[i] = o.u;
}

// ---------------- proj1: thread = output column; xl split into two 64-ch fp8 tables ----------------
__global__ __launch_bounds__(256) void k_proj1(
        const __half* __restrict__ x16,
        const float* __restrict__ wl, const float* __restrict__ bl,
        const float* __restrict__ wr, const float* __restrict__ br,
        unsigned char* __restrict__ xl8a, unsigned char* __restrict__ xl8b,
        __half* __restrict__ xr16, int N) {
    int t = threadIdx.x;
    bool isL = t < 128;
    int j = isL ? t : t - 128;
    const float* w = isL ? wl : wr;
    float bj = isL ? bl[j] : br[j];
    f16x2 wreg[32];
#pragma unroll
    for (int k = 0; k < 32; ++k)
        wreg[k] = (f16x2){(_Float16)w[(2*k) * HID + j], (_Float16)w[(2*k+1) * HID + j]};
    unsigned char* xl8p = (j < 64) ? xl8a : xl8b;
    int jc = j & 63;
    for (int n = blockIdx.x; n < N; n += gridDim.x) {
        X8 xa;
        const uint4* xp = (const uint4*)(x16 + (size_t)n * DIN);
#pragma unroll
        for (int q = 0; q < 8; ++q) xa.u4[q] = xp[q];
        float acc = 0.f;
#pragma unroll
        for (int k = 0; k < 32; ++k) acc = __builtin_amdgcn_fdot2(xa.h[k], wreg[k], acc, false);
        acc += bj;
        if (isL) xl8p[(size_t)n * 64 + jc] = to_fp8(acc);
        else     xr16[(size_t)n * HID + j] = __float2half(acc);
    }
}

// ---------------- proj2: thread = output column (128 cols: 64 w2l -> fp8, 64 w2r -> f16) ----------------
__global__ __launch_bounds__(128) void k_proj2(
        const __half* __restrict__ h1,
        const float* __restrict__ wl, const float* __restrict__ bl,
        const float* __restrict__ wr, const float* __restrict__ br,
        unsigned char* __restrict__ xl8, __half* __restrict__ xr16, int N) {
    int t = threadIdx.x;
    bool isL = t < 64;
    int j = isL ? t : t - 64;
    const float* w = isL ? wl : wr;
    float bj = isL ? bl[j] : br[j];
    f16x2 wreg0[32], wreg1[32];
#pragma unroll
    for (int k = 0; k < 32; ++k) {
        wreg0[k] = (f16x2){(_Float16)w[(2*k) * DOUT + j], (_Float16)w[(2*k+1) * DOUT + j]};
        wreg1[k] = (f16x2){(_Float16)w[(64 + 2*k) * DOUT + j], (_Float16)w[(64 + 2*k+1) * DOUT + j]};
    }
    for (int n = blockIdx.x; n < N; n += gridDim.x) {
        const uint4* xp = (const uint4*)(h1 + (size_t)n * HID);
        float acc = 0.f;
        {
            X8 xa;
#pragma unroll
            for (int q = 0; q < 8; ++q) xa.u4[q] = xp[q];
#pragma unroll
            for (int k = 0; k < 32; ++k) acc = __builtin_amdgcn_fdot2(xa.h[k], wreg0[k], acc, false);
        }
        {
            X8 xa;
#pragma unroll
            for (int q = 0; q < 8; ++q) xa.u4[q] = xp[8 + q];
#pragma unroll
            for (int k = 0; k < 32; ++k) acc = __builtin_amdgcn_fdot2(xa.h[k], wreg1[k], acc, false);
        }
        acc += bj;
        if (isL) xl8[(size_t)n * DOUT + j] = to_fp8(acc);
        else     xr16[(size_t)n * DOUT + j] = __float2half(acc);
    }
}

// ---------------- layer-1 head-split pass: 4 heads (64 ch), L2-resident 3.2MB table ----------------
// lane = es(4b)*4 + q4(2b); q4 = head-in-pass (16 ch); logit fully lane-local.
#define GP_FETCH(R, SLOT) \
    rec##R = __shfl(creg, (SLOT) * 16 + es); \
    buf##R = *(const uint4*)(xl8p + ((rec##R & 0xFFFFu) * 64u + (unsigned)cb));

#define GP_COMP(R, SLOT) { \
    f16x2 xv[8]; \
    cvt16(buf##R, xv); \
    bool live = (s0 + (SLOT) * 16 + es) < r1; \
    _Float16 wh = us2h((unsigned short)(rec##R >> 16)); \
    f16x2 w2 = (f16x2){wh, wh}; \
    float p0 = 0.f, p1 = 0.f; \
    _Pragma("unroll") \
    for (int k = 0; k < 8; k += 2) { \
        f16x2 m0 = xv[k] + __builtin_elementwise_fma(w2, we2[k], xr.h[k]); \
        m0 = __builtin_elementwise_max(m0, m0 * c02); \
        p0 = __builtin_amdgcn_fdot2(m0, at2[k], p0, false); \
        f16x2 m1 = xv[k+1] + __builtin_elementwise_fma(w2, we2[k+1], xr.h[k+1]); \
        m1 = __builtin_elementwise_max(m1, m1 * c02); \
        p1 = __builtin_amdgcn_fdot2(m1, at2[k+1], p1, false); \
    } \
    float ex = live ? __expf(p0 + p1) : 0.f; \
    den += ex; \
    _Float16 exh = (_Float16)ex; \
    f16x2 ex2 = (f16x2){exh, exh}; \
    _Pragma("unroll") \
    for (int k = 0; k < 8; ++k) num2[k] = __builtin_elementwise_fma(ex2, xv[k], num2[k]); }

__global__ __launch_bounds__(256) void k_gat1p(
        const int* __restrict__ rowptr, const unsigned* __restrict__ csr,
        const unsigned char* __restrict__ xl8p, const __half* __restrict__ xr16,
        const float* __restrict__ w1e, const float* __restrict__ att,
        const float* __restrict__ bias, __half* __restrict__ h1,
        int N, int totWaves, int po) {
    int lane = threadIdx.x & 63;
    int wv = (blockIdx.x * blockDim.x + threadIdx.x) >> 6;
    int q4 = lane & 3, es = lane >> 2;
    int cb = q4 * 16;
    int cown = cb + es;
    f16x2 we2[8], at2[8];
#pragma unroll
    for (int k = 0; k < 8; ++k) {
        we2[k] = (f16x2){(_Float16)w1e[po + cb + 2*k], (_Float16)w1e[po + cb + 2*k + 1]};
        at2[k] = (f16x2){(_Float16)att[po + cb + 2*k], (_Float16)att[po + cb + 2*k + 1]};
    }
    float bso = bias[po + cown];
    const f16x2 c02 = (f16x2){(_Float16)0.2f, (_Float16)0.2f};

    int r0 = 0, r1 = 0;
    if (wv < N) { r0 = rowptr[wv]; r1 = rowptr[wv + 1]; }
    for (int n = wv; n < N; n += totWaves) {
        int nn = n + totWaves;
        int r0n = 0, r1n = 0;
        if (nn < N) { r0n = rowptr[nn]; r1n = rowptr[nn + 1]; }

        U8 xr;
        { const uint4* p = (const uint4*)(xr16 + (unsigned)(n * HID + po + cb)); xr.u4[0] = p[0]; xr.u4[1] = p[1]; }
        float den = 0.f;
        f16x2 num2[8];
#pragma unroll
        for (int k = 0; k < 8; ++k) num2[k] = (f16x2){(_Float16)0.f, (_Float16)0.f};

        for (int s0 = r0; s0 < r1; s0 += 64) {
            unsigned creg = csr[min(s0 + lane, r1 - 1)];
            unsigned recA, recB, recC;
            uint4 bufA, bufB, bufC;
            GP_FETCH(A, 0)
            GP_FETCH(B, 1)
            GP_FETCH(C, 2)
            GP_COMP(A, 0)
            if (s0 + 48 < r1) { GP_FETCH(A, 3) }
            if (s0 + 16 < r1) {
                GP_COMP(B, 1)
                if (s0 + 32 < r1) {
                    GP_COMP(C, 2)
                    if (s0 + 48 < r1) {
                        GP_COMP(A, 3)
                    }
                }
            }
        }
        // den reduce over es (per-lane head q4 kept intact)
        den += __shfl_xor(den, 4); den += __shfl_xor(den, 8);
        den += __shfl_xor(den, 16); den += __shfl_xor(den, 32);
        // num reduce-scatter over es -> lane owns channel cb+es
        bool b8 = es & 8, b4 = es & 4, b2 = es & 2;
        f16x2 r4[4];
#pragma unroll
        for (int k = 0; k < 4; ++k) {
            f16x2 send_ = b8 ? num2[k] : num2[k + 4];
            f16x2 recv = i2h(__shfl_xor(h2i(send_), 32));
            r4[k] = (b8 ? num2[k + 4] : num2[k]) + recv;
        }
        f16x2 r2[2];
#pragma unroll
        for (int k = 0; k < 2; ++k) {
            f16x2 send_ = b4 ? r4[k] : r4[k + 2];
            f16x2 recv = i2h(__shfl_xor(h2i(send_), 16));
            r2[k] = (b4 ? r4[k + 2] : r4[k]) + recv;
        }
        f16x2 send1 = b2 ? r2[0] : r2[1];
        f16x2 recv1 = i2h(__shfl_xor(h2i(send1), 8));
        f16x2 r1v = (b2 ? r2[1] : r2[0]) + recv1;
        f16x2 rsum = r1v + i2h(__shfl_xor(h2i(r1v), 4));
        float o = (es & 1) ? (float)rsum[1] : (float)rsum[0];
        float v = fmaf(o, 1.f / den, bso);
        v = v > 0.f ? v : expm1f(v);   // ELU
        h1[(unsigned)(n * HID + po + cown)] = __float2half(v);
        r0 = r0n; r1 = r1n;
    }
}

// ---------------- layer-2 fused GAT: depth-3, 4 slots of 16 edges + log_softmax + fc ----------------
#define G2_FETCH(R, SLOT) \
    rec##R = __shfl(creg, (SLOT) * 16 + es); \
    buf##R = *(const uint4*)(xl8 + ((rec##R & 0xFFFFu) * 64u + (unsigned)cb));

#define G2_COMP(R, SLOT) { \
    f16x2 xv[8]; \
    cvt16(buf##R, xv); \
    bool live = (s0 + (SLOT) * 16 + es) < r1; \
    _Float16 wh = us2h((unsigned short)(rec##R >> 16)); \
    f16x2 w2 = (f16x2){wh, wh}; \
    float p0 = 0.f, p1 = 0.f; \
    _Pragma("unroll") \
    for (int k = 0; k < 8; k += 2) { \
        f16x2 m0 = xv[k] + __builtin_elementwise_fma(w2, we2[k], xr.h[k]); \
        m0 = __builtin_elementwise_max(m0, m0 * c02); \
        p0 = __builtin_amdgcn_fdot2(m0, at2[k], p0, false); \
        f16x2 m1 = xv[k+1] + __builtin_elementwise_fma(w2, we2[k+1], xr.h[k+1]); \
        m1 = __builtin_elementwise_max(m1, m1 * c02); \
        p1 = __builtin_amdgcn_fdot2(m1, at2[k+1], p1, false); \
    } \
    float p = p0 + p1; \
    p += __shfl_xor(p, 1); \
    p += __shfl_xor(p, 2); \
    float ex = live ? __expf(p) : 0.f; \
    den += ex; \
    _Float16 exh = (_Float16)ex; \
    f16x2 ex2 = (f16x2){exh, exh}; \
    _Pragma("unroll") \
    for (int k = 0; k < 8; ++k) num2[k] = __builtin_elementwise_fma(ex2, xv[k], num2[k]); }

__global__ __launch_bounds__(256) void k_gat2(
        const int* __restrict__ rowptr, const unsigned* __restrict__ csr,
        const unsigned char* __restrict__ xl8, const __half* __restrict__ xr16,
        const float* __restrict__ w2e, const float* __restrict__ att,
        const float* __restrict__ bias2, const float* __restrict__ fcw,
        const float* __restrict__ fcb, float* __restrict__ out,
        int N, int totWaves) {
    int lane = threadIdx.x & 63;
    int wv = (blockIdx.x * blockDim.x + threadIdx.x) >> 6;
    int q4 = lane & 3, es = lane >> 2;
    int cb = q4 * 16;
    int cown = cb + es;
    f16x2 we2[8], at2[8];
#pragma unroll
    for (int k = 0; k < 8; ++k) {
        we2[k] = (f16x2){(_Float16)w2e[cb + 2*k], (_Float16)w2e[cb + 2*k + 1]};
        at2[k] = (f16x2){(_Float16)att[cb + 2*k], (_Float16)att[cb + 2*k + 1]};
    }
    float bso = bias2[cown], fcwo = fcw[cown], fcb0 = fcb[0];
    const f16x2 c02 = (f16x2){(_Float16)0.2f, (_Float16)0.2f};

    int r0 = 0, r1 = 0;
    if (wv < N) { r0 = rowptr[wv]; r1 = rowptr[wv + 1]; }
    for (int n = wv; n < N; n += totWaves) {
        int nn = n + totWaves;
        int r0n = 0, r1n = 0;
        if (nn < N) { r0n = rowptr[nn]; r1n = rowptr[nn + 1]; }

        U8 xr;
        { const uint4* p = (const uint4*)(xr16 + (unsigned)(n * DOUT + cb)); xr.u4[0] = p[0]; xr.u4[1] = p[1]; }
        float den = 0.f;
        f16x2 num2[8];
#pragma unroll
        for (int k = 0; k < 8; ++k) num2[k] = (f16x2){(_Float16)0.f, (_Float16)0.f};

        for (int s0 = r0; s0 < r1; s0 += 64) {
            unsigned creg = csr[min(s0 + lane, r1 - 1)];
            unsigned recA, recB, recC;
            uint4 bufA, bufB, bufC;
            G2_FETCH(A, 0)
            G2_FETCH(B, 1)
            G2_FETCH(C, 2)
            G2_COMP(A, 0)
            if (s0 + 48 < r1) { G2_FETCH(A, 3) }
            if (s0 + 16 < r1) {
                G2_COMP(B, 1)
                if (s0 + 32 < r1) {
                    G2_COMP(C, 2)
                    if (s0 + 48 < r1) {
                        G2_COMP(A, 3)
                    }
                }
            }
        }
        den += __shfl_xor(den, 4); den += __shfl_xor(den, 8);
        den += __shfl_xor(den, 16); den += __shfl_xor(den, 32);
        bool b8 = es & 8, b4 = es & 4, b2 = es & 2;
        f16x2 r4[4];
#pragma unroll
        for (int k = 0; k < 4; ++k) {
            f16x2 send_ = b8 ? num2[k] : num2[k + 4];
            f16x2 recv = i2h(__shfl_xor(h2i(send_), 32));
            r4[k] = (b8 ? num2[k + 4] : num2[k]) + recv;
        }
        f16x2 r2[2];
#pragma unroll
        for (int k = 0; k < 2; ++k) {
            f16x2 send_ = b4 ? r4[k] : r4[k + 2];
            f16x2 recv = i2h(__shfl_xor(h2i(send_), 16));
            r2[k] = (b4 ? r4[k + 2] : r4[k]) + recv;
        }
        f16x2 send1 = b2 ? r2[0] : r2[1];
        f16x2 recv1 = i2h(__shfl_xor(h2i(send1), 8));
        f16x2 r1v = (b2 ? r2[1] : r2[0]) + recv1;
        f16x2 rsum = r1v + i2h(__shfl_xor(h2i(r1v), 4));
        float o = (es & 1) ? (float)rsum[1] : (float)rsum[0];
        o = fmaf(o, 1.f / den, bso);
        float mx = o;
#pragma unroll
        for (int off = 1; off < 64; off <<= 1) mx = fmaxf(mx, __shfl_xor(mx, off));
        float exv = __expf(o - mx);
        float ssum = exv;
#pragma unroll
        for (int off = 1; off < 64; off <<= 1) ssum += __shfl_xor(ssum, off);
        float ls = o - mx - __logf(ssum);
        float contrib = ls * fcwo;
#pragma unroll
        for (int off = 1; off < 64; off <<= 1) contrib += __shfl_xor(contrib, off);
        if (lane == 0) out[n] = contrib + fcb0;
        r0 = r0n; r1 = r1n;
    }
}

extern "C" void kernel_launch(void* const* d_in, const int* in_sizes, int n_in,
                              void* d_out, int out_size, void* d_ws, size_t ws_size,
                              hipStream_t stream) {
    const float* x     = (const float*)d_in[0];
    const int*   ei    = (const int*)d_in[1];
    const float* ew    = (const float*)d_in[2];
    const float* w1l   = (const float*)d_in[3];
    const float* b1l   = (const float*)d_in[4];
    const float* w1r   = (const float*)d_in[5];
    const float* b1r   = (const float*)d_in[6];
    const float* w1e   = (const float*)d_in[7];
    const float* att1  = (const float*)d_in[8];
    const float* bias1 = (const float*)d_in[9];
    const float* w2l   = (const float*)d_in[10];
    const float* b2l   = (const float*)d_in[11];
    const float* w2r   = (const float*)d_in[12];
    const float* b2r   = (const float*)d_in[13];
    const float* w2e   = (const float*)d_in[14];
    const float* att2  = (const float*)d_in[15];
    const float* bias2 = (const float*)d_in[16];
    const float* fcw   = (const float*)d_in[17];
    const float* fcb   = (const float*)d_in[18];
    float* out = (float*)d_out;

    int N = in_sizes[0] / DIN;
    int E = in_sizes[1] / 2;
    int Etot = E + N;
    int NB = (N + BS - 1) >> BSH;   // 196 buckets (<=256)

    char* base = (char*)d_ws;
    size_t off = 0;
    auto alloc = [&](size_t bytes) -> void* {
        void* p = base + off;
        off += (bytes + 15) & ~(size_t)15;
        return p;
    };
    int*      rowptr = (int*)alloc(((size_t)N + 1) * 4);
    unsigned* csr    = (unsigned*)alloc((size_t)Etot * 4);
    int*      h      = (int*)alloc((size_t)NB * NBLK * 4);
    int*      Btot   = (int*)alloc((size_t)NB * 4);
    int*      Boff   = (int*)alloc(((size_t)NB + 1) * 4);
    // region R: [xl8a (N*64) | xl8b (N*64) | xr16 (N*128*2)] aliased by barr (E*8 = 12.9 MB <= 19.2 MB);
    // barr dead before k_proj1 writes (stream-ordered after k_csr).
    char* R = (char*)alloc((size_t)N * HID * 3);
    int2*          barr = (int2*)R;
    unsigned char* xl8a = (unsigned char*)R;
    unsigned char* xl8b = (unsigned char*)(R + (size_t)N * 64);
    __half*        xr16 = (__half*)(R + (size_t)N * HID * 1);
    __half*        h1   = (__half*)alloc((size_t)N * HID * 2);
    __half*        x16  = (__half*)alloc((size_t)N * DIN * 2);
    (void)ws_size;

    // CSR build: deterministic two-level bucket sort (no global atomics)
    k_hist<<<NBLK, 256, 0, stream>>>(ei, h, E, NB);
    k_scancol<<<NB, 256, 0, stream>>>(h, Btot, NB);
    k_scanbuck<<<1, 256, 0, stream>>>(Btot, Boff, rowptr, E, N, NB);
    k_scatter<<<NBLK, 256, 0, stream>>>(ei, ew, h, Boff, barr, E, NB);
    k_csr<<<NB, 512, 0, stream>>>(barr, Boff, rowptr, csr, N, NB);

    // x -> f16
    int tot8 = N * DIN / 8;
    k_x16<<<(tot8 + 255) / 256, 256, 0, stream>>>(x, x16, tot8);

    // full residency: 2048 blocks x 256 thr = 8192 waves
    const int GB = 2048, TB = 256;
    int totWaves = GB * (TB / 64);

    // layer 1: head-split two-pass (each pass's 3.2MB fp8 table is L2-resident)
    k_proj1<<<2048, 256, 0, stream>>>(x16, w1l, b1l, w1r, b1r, xl8a, xl8b, xr16, N);
    k_gat1p<<<GB, TB, 0, stream>>>(rowptr, csr, xl8a, xr16, w1e, att1, bias1, h1, N, totWaves, 0);
    k_gat1p<<<GB, TB, 0, stream>>>(rowptr, csr, xl8b, xr16, w1e, att1, bias1, h1, N, totWaves, 64);

    // layer 2 (reuse xl8a/xr16 regions; stream-ordered)
    k_proj2<<<2048, 128, 0, stream>>>(h1, w2l, b2l, w2r, b2r, xl8a, xr16, N);
    k_gat2<<<GB, TB, 0, stream>>>(rowptr, csr, xl8a, xr16, w2e, att2, bias2, fcw, fcb, out, N, totWaves);
}

// Round 16
// 206.808 us; speedup vs baseline: 1.0983x; 1.0983x over previous
//
#include <hip/hip_runtime.h>
#include <hip/hip_fp16.h>

#define HEADS 8
#define HID 128
#define DIN 64
#define DOUT 64
#define NBLK 512      // blocks for hist/scatter passes
#define BSH 8         // bucket shift: bucket = dst >> 8
#define BS 256        // nodes per bucket
#define MAXNB 512     // LDS capacity (NB = ceil(50000/256) = 196)

typedef _Float16 f16x2 __attribute__((ext_vector_type(2)));
union U8 { uint4 u4[2]; f16x2 h[8]; };
union X8 { uint4 u4[8]; f16x2 h[32]; };

__device__ __forceinline__ int h2i(f16x2 h) { union { f16x2 h; int i; } u; u.h = h; return u.i; }
__device__ __forceinline__ f16x2 i2h(int i) { union { f16x2 h; int i; } u; u.i = i; return u.h; }
__device__ __forceinline__ _Float16 us2h(unsigned short v) { union { unsigned short u; _Float16 h; } u; u.u = v; return u.h; }

// decode 16 fp8(e4m3) -> 8 x f16x2
__device__ __forceinline__ void cvt16(const uint4 v, f16x2* o) {
#if __has_builtin(__builtin_amdgcn_cvt_scalef32_pk_f16_fp8)
    o[0] = __builtin_amdgcn_cvt_scalef32_pk_f16_fp8(v.x, 1.0f, false);
    o[1] = __builtin_amdgcn_cvt_scalef32_pk_f16_fp8(v.x, 1.0f, true);
    o[2] = __builtin_amdgcn_cvt_scalef32_pk_f16_fp8(v.y, 1.0f, false);
    o[3] = __builtin_amdgcn_cvt_scalef32_pk_f16_fp8(v.y, 1.0f, true);
    o[4] = __builtin_amdgcn_cvt_scalef32_pk_f16_fp8(v.z, 1.0f, false);
    o[5] = __builtin_amdgcn_cvt_scalef32_pk_f16_fp8(v.z, 1.0f, true);
    o[6] = __builtin_amdgcn_cvt_scalef32_pk_f16_fp8(v.w, 1.0f, false);
    o[7] = __builtin_amdgcn_cvt_scalef32_pk_f16_fp8(v.w, 1.0f, true);
#else
    const f16x2 s256 = (f16x2){(_Float16)256.f, (_Float16)256.f};
    const unsigned* uu = &v.x;
#pragma unroll
    for (int j = 0; j < 4; ++j) {
        unsigned u = uu[j];
        unsigned plo = u & 0xFFFFu, phi = u >> 16;
        unsigned flo = ((plo & 0x80u) << 8) | ((plo & 0x7Fu) << 7)
                     | ((plo & 0x8000u) << 16) | ((plo & 0x7F00u) << 15);
        unsigned fhi = ((phi & 0x80u) << 8) | ((phi & 0x7Fu) << 7)
                     | ((phi & 0x8000u) << 16) | ((phi & 0x7F00u) << 15);
        o[2*j]   = i2h((int)flo) * s256;   // exact: fp8 bits as f16, exponent fixed by *2^8
        o[2*j+1] = i2h((int)fhi) * s256;
    }
#endif
}

__device__ __forceinline__ unsigned enc_fp8(float a) {
    float c = fminf(fmaxf(a, -448.f), 448.f);
    unsigned short hb = __half_as_ushort(__float2half(c));
    unsigned s = ((unsigned)hb >> 8) & 0x80u;
    unsigned lsb = (hb >> 7) & 1u;
    unsigned hr = (unsigned)hb + 0x3Fu + lsb;      // RNE at bit 7
    int e = (int)((hr >> 10) & 0x1Fu);
    if (e <= 8) {                                   // |c| < ~2^-6: subnormal fp8
        int m8 = (int)rintf(fabsf(c) * 512.f);
        if (m8 >= 8) return s | (1u << 3);
        return s | (unsigned)m8;
    }
    unsigned m3 = (hr >> 7) & 7u;
    int ef = e - 8;
    if (ef > 15) { ef = 15; m3 = 7u; }
    return s | ((unsigned)ef << 3) | m3;
}

__device__ __forceinline__ unsigned char to_fp8(float a) {
#if __has_builtin(__builtin_amdgcn_cvt_pk_fp8_f32)
    int v = __builtin_amdgcn_cvt_pk_fp8_f32(a, a, 0, false);
    return (unsigned char)(v & 0xFF);
#else
    return (unsigned char)enc_fp8(a);
#endif
}

// ---------------- A1: per-(block,bucket) histogram (bucket-major output) ----------------
__global__ void k_hist(const int* __restrict__ ei, int* __restrict__ h, int E, int NB) {
    __shared__ int hist[MAXNB];
    int i = blockIdx.x, t = threadIdx.x;
    for (int b = t; b < NB; b += 256) hist[b] = 0;
    __syncthreads();
    int chunk = (E + NBLK - 1) / NBLK;
    int e0 = i * chunk, e1 = min(E, e0 + chunk);
    for (int e = e0 + t; e < e1; e += 256) {
        int d = ei[E + e];
        atomicAdd(&hist[d >> BSH], 1);
    }
    __syncthreads();
    for (int b = t; b < NB; b += 256) h[b * NBLK + i] = hist[b];
}

// ---------------- A2a: parallel per-bucket column scan (coalesced) ----------------
__global__ void k_scancol(int* __restrict__ h, int* __restrict__ Btot, int NB) {
    __shared__ int s[256];
    int b = blockIdx.x, t = threadIdx.x;
    int* col = h + (size_t)b * NBLK;
    int v0 = col[2 * t], v1 = col[2 * t + 1];
    int pair = v0 + v1;
    s[t] = pair;
    __syncthreads();
    for (int off = 1; off < 256; off <<= 1) {
        int u = (t >= off) ? s[t - off] : 0;
        __syncthreads();
        s[t] += u;
        __syncthreads();
    }
    int excl = s[t] - pair;
    col[2 * t] = excl;
    col[2 * t + 1] = excl + v0;
    if (t == 255) Btot[b] = s[255];
}

// ---------------- A2b: bucket-level scan ----------------
__global__ void k_scanbuck(const int* __restrict__ Btot, int* __restrict__ Boff,
                           int* __restrict__ rowptr, int E, int N, int NB) {
    __shared__ int s[256];
    int t = threadIdx.x;
    int v = (t < NB) ? Btot[t] : 0;
    s[t] = v;
    __syncthreads();
    for (int off = 1; off < 256; off <<= 1) {
        int u = (t >= off) ? s[t - off] : 0;
        __syncthreads();
        s[t] += u;
        __syncthreads();
    }
    if (t < NB) Boff[t] = s[t] - v;
    if (t == 0) { Boff[NB] = E; rowptr[N] = E + N; }
}

// ---------------- A3: scatter records into bucket-sorted staging ----------------
__global__ void k_scatter(const int* __restrict__ ei, const float* __restrict__ ew,
                          const int* __restrict__ h, const int* __restrict__ Boff,
                          int2* __restrict__ barr, int E, int NB) {
    __shared__ int base[MAXNB];
    int i = blockIdx.x, t = threadIdx.x;
    for (int b = t; b < NB; b += 256) base[b] = h[b * NBLK + i] + Boff[b];
    __syncthreads();
    int chunk = (E + NBLK - 1) / NBLK;
    int e0 = i * chunk, e1 = min(E, e0 + chunk);
    for (int e = e0 + t; e < e1; e += 256) {
        int s = ei[e], d = ei[E + e];
        float w = ew[e];
        int slot = atomicAdd(&base[d >> BSH], 1);   // LDS atomic; disjoint ranges
        barr[slot] = make_int2(((d & (BS - 1)) << 16) | s, __float_as_int(w));
    }
}

// ---------------- B: bucket -> exact CSR; 512 threads for latency hiding ----------------
__global__ __launch_bounds__(512) void k_csr(
        const int2* __restrict__ barr, const int* __restrict__ Boff,
        int* __restrict__ rowptr, unsigned* __restrict__ csrw, int N, int NB) {
    __shared__ int cnt[BS];
    __shared__ int wfix[BS];
    __shared__ int off[BS];
    __shared__ int fill[BS];
    int b = blockIdx.x, t = threadIdx.x;
    int n0 = b << BSH;
    int nodes = min(BS, N - n0);
    if (t < BS) { cnt[t] = 0; wfix[t] = 0; }
    __syncthreads();
    int j0 = Boff[b], j1 = Boff[b + 1];
    for (int j = j0 + t; j < j1; j += 512) {
        int2 rec = barr[j];
        int dl = rec.x >> 16;
        atomicAdd(&cnt[dl], 1);
        atomicAdd(&wfix[dl], (int)(__int_as_float(rec.y) * 16777216.0f));  // 2^24 fixed-point
    }
    __syncthreads();
    int v = 0;
    if (t < BS) {
        v = (t < nodes) ? cnt[t] + 1 : 0;   // +1 self loop
        off[t] = v;
    }
    __syncthreads();
    for (int o = 1; o < BS; o <<= 1) {
        int u = 0;
        if (t < BS && t >= o) u = off[t - o];
        __syncthreads();
        if (t < BS) off[t] += u;
        __syncthreads();
    }
    int rowBase = j0 + n0;
    if (t < nodes) {
        int rs = rowBase + off[t] - v;
        rowptr[n0 + t] = rs;
        int c = cnt[t];
        float mean = (c > 0) ? ((float)wfix[t] * (1.f / 16777216.f)) / (float)c : 0.f;
        csrw[rs + c] = (unsigned)(n0 + t)
                     | ((unsigned)__half_as_ushort(__float2half(mean)) << 16);  // self-loop
        fill[t] = rs;
    }
    __syncthreads();
    for (int j = j0 + t; j < j1; j += 512) {
        int2 rec = barr[j];
        int dl = rec.x >> 16;
        int pos = atomicAdd(&fill[dl], 1);
        unsigned wb = (unsigned)__half_as_ushort(__float2half(__int_as_float(rec.y)));
        csrw[pos] = (unsigned)(rec.x & 0xFFFF) | (wb << 16);
    }
}

// ---------------- x f32 -> f16 (8 values/thread) ----------------
__global__ void k_x16(const float* __restrict__ x, __half* __restrict__ x16, int total8) {
    int i = blockIdx.x * blockDim.x + threadIdx.x;
    if (i >= total8) return;
    const float4* p = (const float4*)(x + (size_t)i * 8);
    float4 a = p[0], b = p[1];
    union { __half h[8]; uint4 u; } o;
    o.h[0] = __float2half(a.x); o.h[1] = __float2half(a.y);
    o.h[2] = __float2half(a.z); o.h[3] = __float2half(a.w);
    o.h[4] = __float2half(b.x); o.h[5] = __float2half(b.y);
    o.h[6] = __float2half(b.z); o.h[7] = __float2half(b.w);
    ((uint4*)x16)[i] = o.u;
}

// ---------------- proj1: thread = output column (256 cols: 128 wl -> fp8, 128 wr -> f16) ----------------
__global__ __launch_bounds__(256) void k_proj1(
        const __half* __restrict__ x16,
        const float* __restrict__ wl, const float* __restrict__ bl,
        const float* __restrict__ wr, const float* __restrict__ br,
        unsigned char* __restrict__ xl8, __half* __restrict__ xr16, int N) {
    int t = threadIdx.x;
    bool isL = t < 128;
    int j = isL ? t : t - 128;
    const float* w = isL ? wl : wr;
    float bj = isL ? bl[j] : br[j];
    f16x2 wreg[32];
#pragma unroll
    for (int k = 0; k < 32; ++k)
        wreg[k] = (f16x2){(_Float16)w[(2*k) * HID + j], (_Float16)w[(2*k+1) * HID + j]};
    for (int n = blockIdx.x; n < N; n += gridDim.x) {
        X8 xa;
        const uint4* xp = (const uint4*)(x16 + (size_t)n * DIN);
#pragma unroll
        for (int q = 0; q < 8; ++q) xa.u4[q] = xp[q];
        float acc = 0.f;
#pragma unroll
        for (int k = 0; k < 32; ++k) acc = __builtin_amdgcn_fdot2(xa.h[k], wreg[k], acc, false);
        acc += bj;
        if (isL) xl8[(size_t)n * HID + j] = to_fp8(acc);
        else     xr16[(size_t)n * HID + j] = __float2half(acc);
    }
}

// ---------------- proj2: thread = output column (128 cols: 64 w2l -> fp8, 64 w2r -> f16) ----------------
__global__ __launch_bounds__(128) void k_proj2(
        const __half* __restrict__ h1,
        const float* __restrict__ wl, const float* __restrict__ bl,
        const float* __restrict__ wr, const float* __restrict__ br,
        unsigned char* __restrict__ xl8, __half* __restrict__ xr16, int N) {
    int t = threadIdx.x;
    bool isL = t < 64;
    int j = isL ? t : t - 64;
    const float* w = isL ? wl : wr;
    float bj = isL ? bl[j] : br[j];
    f16x2 wreg0[32], wreg1[32];
#pragma unroll
    for (int k = 0; k < 32; ++k) {
        wreg0[k] = (f16x2){(_Float16)w[(2*k) * DOUT + j], (_Float16)w[(2*k+1) * DOUT + j]};
        wreg1[k] = (f16x2){(_Float16)w[(64 + 2*k) * DOUT + j], (_Float16)w[(64 + 2*k+1) * DOUT + j]};
    }
    for (int n = blockIdx.x; n < N; n += gridDim.x) {
        const uint4* xp = (const uint4*)(h1 + (size_t)n * HID);
        float acc = 0.f;
        {
            X8 xa;
#pragma unroll
            for (int q = 0; q < 8; ++q) xa.u4[q] = xp[q];
#pragma unroll
            for (int k = 0; k < 32; ++k) acc = __builtin_amdgcn_fdot2(xa.h[k], wreg0[k], acc, false);
        }
        {
            X8 xa;
#pragma unroll
            for (int q = 0; q < 8; ++q) xa.u4[q] = xp[8 + q];
#pragma unroll
            for (int k = 0; k < 32; ++k) acc = __builtin_amdgcn_fdot2(xa.h[k], wreg1[k], acc, false);
        }
        acc += bj;
        if (isL) xl8[(size_t)n * DOUT + j] = to_fp8(acc);
        else     xr16[(size_t)n * DOUT + j] = __float2half(acc);
    }
}

// ---------------- layer-1 fused GAT: HALF-WAVE per node (2 nodes/wave), depth-3 ----------------
// lane = half(1b)*32 + head(3b)*4 + es(2b); chunk = 64 edges/node, 16 slots of 4
#define G1_FETCH(R, SLOT) \
    rec##R = __shfl(((SLOT) < 8 ? creg0 : creg1), (lane & 32) | (((SLOT) & 7) * 4 + es)); \
    buf##R = *(const uint4*)(xl8 + ((rec##R & 0xFFFFu) * 128u + (unsigned)cb));

#define G1_COMP(R, SLOT) { \
    f16x2 xv[8]; \
    cvt16(buf##R, xv); \
    bool live = (crel + (SLOT) * 4 + es) < d; \
    _Float16 wh = us2h((unsigned short)(rec##R >> 16)); \
    f16x2 w2 = (f16x2){wh, wh}; \
    float p0 = 0.f, p1 = 0.f; \
    _Pragma("unroll") \
    for (int k = 0; k < 8; k += 2) { \
        f16x2 m0 = xv[k] + __builtin_elementwise_fma(w2, we2[k], xr.h[k]); \
        m0 = __builtin_elementwise_max(m0, m0 * c02); \
        p0 = __builtin_amdgcn_fdot2(m0, at2[k], p0, false); \
        f16x2 m1 = xv[k+1] + __builtin_elementwise_fma(w2, we2[k+1], xr.h[k+1]); \
        m1 = __builtin_elementwise_max(m1, m1 * c02); \
        p1 = __builtin_amdgcn_fdot2(m1, at2[k+1], p1, false); \
    } \
    float ex = live ? __expf(p0 + p1) : 0.f; \
    den += ex; \
    _Float16 exh = (_Float16)ex; \
    f16x2 ex2 = (f16x2){exh, exh}; \
    _Pragma("unroll") \
    for (int k = 0; k < 8; ++k) num2[k] = __builtin_elementwise_fma(ex2, xv[k], num2[k]); }

__global__ __launch_bounds__(256) void k_gat1(
        const int* __restrict__ rowptr, const unsigned* __restrict__ csr,
        const unsigned char* __restrict__ xl8, const __half* __restrict__ xr16,
        const float* __restrict__ w1e, const float* __restrict__ att,
        const float* __restrict__ bias, __half* __restrict__ h1,
        int N, int totWaves) {
    int lane = threadIdx.x & 63;
    int wv = (blockIdx.x * blockDim.x + threadIdx.x) >> 6;
    int half = lane >> 5;
    int hl = lane & 31;
    int es = hl & 3, hd = hl >> 2;
    int cb = hd * 16;
    f16x2 we2[8], at2[8];
#pragma unroll
    for (int k = 0; k < 8; ++k) {
        we2[k] = (f16x2){(_Float16)w1e[cb + 2*k], (_Float16)w1e[cb + 2*k + 1]};
        at2[k] = (f16x2){(_Float16)att[cb + 2*k], (_Float16)att[cb + 2*k + 1]};
    }
    float4 bs4 = *(const float4*)(bias + cb + es * 4);
    const f16x2 c02 = (f16x2){(_Float16)0.2f, (_Float16)0.2f};

    // N is even (pn even, pn < N => pn+1 < N): both halves always valid
    int pstride = totWaves * 2;
    int pn0 = wv * 2;
    int r0 = 0, r1 = 1;
    if (pn0 < N) { int n = pn0 + half; r0 = rowptr[n]; r1 = rowptr[n + 1]; }
    for (int pn = pn0; pn < N; pn += pstride) {
        int n = pn + half;
        int pnn = pn + pstride;
        int r0n = 0, r1n = 1;
        if (pnn < N) { int nn = pnn + half; r0n = rowptr[nn]; r1n = rowptr[nn + 1]; }

        U8 xr;
        { const uint4* p = (const uint4*)(xr16 + (unsigned)(n * HID + cb)); xr.u4[0] = p[0]; xr.u4[1] = p[1]; }
        float den = 0.f;
        f16x2 num2[8];
#pragma unroll
        for (int k = 0; k < 8; ++k) num2[k] = (f16x2){(_Float16)0.f, (_Float16)0.f};

        int d = r1 - r0;                 // per-half degree (>=1: self-loop)
        int dmax = max(d, __shfl_xor(d, 32));   // wave-uniform pair max
        int r1m1 = r1 - 1;

        for (int crel = 0; crel < dmax; crel += 64) {
            unsigned creg0 = csr[min(r0 + crel + hl, r1m1)];
            unsigned creg1 = csr[min(r0 + crel + 32 + hl, r1m1)];
            unsigned recA, recB, recC;
            uint4 bufA, bufB, bufC;
            G1_FETCH(A, 0)
            G1_FETCH(B, 1)
            G1_FETCH(C, 2)
            G1_COMP(A, 0)  if (crel + 12 < dmax) { G1_FETCH(A, 3) }
            if (crel + 4  < dmax) { G1_COMP(B, 1)  if (crel + 16 < dmax) { G1_FETCH(B, 4) } }
            if (crel + 8  < dmax) { G1_COMP(C, 2)  if (crel + 20 < dmax) { G1_FETCH(C, 5) } }
            if (crel + 12 < dmax) { G1_COMP(A, 3)  if (crel + 24 < dmax) { G1_FETCH(A, 6) } }
            if (crel + 16 < dmax) { G1_COMP(B, 4)  if (crel + 28 < dmax) { G1_FETCH(B, 7) } }
            if (crel + 20 < dmax) { G1_COMP(C, 5)  if (crel + 32 < dmax) { G1_FETCH(C, 8) } }
            if (crel + 24 < dmax) { G1_COMP(A, 6)  if (crel + 36 < dmax) { G1_FETCH(A, 9) } }
            if (crel + 28 < dmax) { G1_COMP(B, 7)  if (crel + 40 < dmax) { G1_FETCH(B, 10) } }
            if (crel + 32 < dmax) { G1_COMP(C, 8)  if (crel + 44 < dmax) { G1_FETCH(C, 11) } }
            if (crel + 36 < dmax) { G1_COMP(A, 9)  if (crel + 48 < dmax) { G1_FETCH(A, 12) } }
            if (crel + 40 < dmax) { G1_COMP(B, 10) if (crel + 52 < dmax) { G1_FETCH(B, 13) } }
            if (crel + 44 < dmax) { G1_COMP(C, 11) if (crel + 56 < dmax) { G1_FETCH(C, 14) } }
            if (crel + 48 < dmax) { G1_COMP(A, 12) if (crel + 60 < dmax) { G1_FETCH(A, 15) } }
            if (crel + 52 < dmax) { G1_COMP(B, 13) }
            if (crel + 56 < dmax) { G1_COMP(C, 14) }
            if (crel + 60 < dmax) { G1_COMP(A, 15) }
        }
        // den all-reduce over es (lane bits 0,1 — stays in half)
        den += __shfl_xor(den, 1); den += __shfl_xor(den, 2);
        // num reduce-scatter over es -> lane owns 4 channels (cb + es*4 ..+3)
        bool e2 = es & 2, e1 = es & 1;
        f16x2 r4[4];
#pragma unroll
        for (int k = 0; k < 4; ++k) {
            f16x2 send_ = e2 ? num2[k] : num2[k + 4];
            f16x2 recv = i2h(__shfl_xor(h2i(send_), 2));
            r4[k] = (e2 ? num2[k + 4] : num2[k]) + recv;
        }
        f16x2 r2[2];
#pragma unroll
        for (int k = 0; k < 2; ++k) {
            f16x2 send_ = e1 ? r4[k] : r4[k + 2];
            f16x2 recv = i2h(__shfl_xor(h2i(send_), 1));
            r2[k] = (e1 ? r4[k + 2] : r4[k]) + recv;
        }
        float inv = 1.f / den;
        float v0 = fmaf((float)r2[0][0], inv, bs4.x);
        float v1 = fmaf((float)r2[0][1], inv, bs4.y);
        float v2 = fmaf((float)r2[1][0], inv, bs4.z);
        float v3 = fmaf((float)r2[1][1], inv, bs4.w);
        v0 = v0 > 0.f ? v0 : expm1f(v0);   // ELU
        v1 = v1 > 0.f ? v1 : expm1f(v1);
        v2 = v2 > 0.f ? v2 : expm1f(v2);
        v3 = v3 > 0.f ? v3 : expm1f(v3);
        union { __half2 h2[2]; uint2 u; } st;
        st.h2[0] = __floats2half2_rn(v0, v1);
        st.h2[1] = __floats2half2_rn(v2, v3);
        *(uint2*)(h1 + (unsigned)(n * HID + cb + es * 4)) = st.u;
        r0 = r0n; r1 = r1n;
    }
}

// ---------------- layer-2 fused GAT: depth-3, 4 slots of 16 edges + log_softmax + fc ----------------
#define G2_FETCH(R, SLOT) \
    rec##R = __shfl(creg, (SLOT) * 16 + es); \
    buf##R = *(const uint4*)(xl8 + ((rec##R & 0xFFFFu) * 64u + (unsigned)cb));

#define G2_COMP(R, SLOT) { \
    f16x2 xv[8]; \
    cvt16(buf##R, xv); \
    bool live = (s0 + (SLOT) * 16 + es) < r1; \
    _Float16 wh = us2h((unsigned short)(rec##R >> 16)); \
    f16x2 w2 = (f16x2){wh, wh}; \
    float p0 = 0.f, p1 = 0.f; \
    _Pragma("unroll") \
    for (int k = 0; k < 8; k += 2) { \
        f16x2 m0 = xv[k] + __builtin_elementwise_fma(w2, we2[k], xr.h[k]); \
        m0 = __builtin_elementwise_max(m0, m0 * c02); \
        p0 = __builtin_amdgcn_fdot2(m0, at2[k], p0, false); \
        f16x2 m1 = xv[k+1] + __builtin_elementwise_fma(w2, we2[k+1], xr.h[k+1]); \
        m1 = __builtin_elementwise_max(m1, m1 * c02); \
        p1 = __builtin_amdgcn_fdot2(m1, at2[k+1], p1, false); \
    } \
    float p = p0 + p1; \
    p += __shfl_xor(p, 1); \
    p += __shfl_xor(p, 2); \
    float ex = live ? __expf(p) : 0.f; \
    den += ex; \
    _Float16 exh = (_Float16)ex; \
    f16x2 ex2 = (f16x2){exh, exh}; \
    _Pragma("unroll") \
    for (int k = 0; k < 8; ++k) num2[k] = __builtin_elementwise_fma(ex2, xv[k], num2[k]); }

__global__ __launch_bounds__(256) void k_gat2(
        const int* __restrict__ rowptr, const unsigned* __restrict__ csr,
        const unsigned char* __restrict__ xl8, const __half* __restrict__ xr16,
        const float* __restrict__ w2e, const float* __restrict__ att,
        const float* __restrict__ bias2, const float* __restrict__ fcw,
        const float* __restrict__ fcb, float* __restrict__ out,
        int N, int totWaves) {
    int lane = threadIdx.x & 63;
    int wv = (blockIdx.x * blockDim.x + threadIdx.x) >> 6;
    int q4 = lane & 3, es = lane >> 2;
    int cb = q4 * 16;
    int cown = cb + es;
    f16x2 we2[8], at2[8];
#pragma unroll
    for (int k = 0; k < 8; ++k) {
        we2[k] = (f16x2){(_Float16)w2e[cb + 2*k], (_Float16)w2e[cb + 2*k + 1]};
        at2[k] = (f16x2){(_Float16)att[cb + 2*k], (_Float16)att[cb + 2*k + 1]};
    }
    float bso = bias2[cown], fcwo = fcw[cown], fcb0 = fcb[0];
    const f16x2 c02 = (f16x2){(_Float16)0.2f, (_Float16)0.2f};

    int r0 = 0, r1 = 0;
    if (wv < N) { r0 = rowptr[wv]; r1 = rowptr[wv + 1]; }
    for (int n = wv; n < N; n += totWaves) {
        int nn = n + totWaves;
        int r0n = 0, r1n = 0;
        if (nn < N) { r0n = rowptr[nn]; r1n = rowptr[nn + 1]; }

        U8 xr;
        { const uint4* p = (const uint4*)(xr16 + (unsigned)(n * DOUT + cb)); xr.u4[0] = p[0]; xr.u4[1] = p[1]; }
        float den = 0.f;
        f16x2 num2[8];
#pragma unroll
        for (int k = 0; k < 8; ++k) num2[k] = (f16x2){(_Float16)0.f, (_Float16)0.f};

        for (int s0 = r0; s0 < r1; s0 += 64) {
            unsigned creg = csr[min(s0 + lane, r1 - 1)];
            unsigned recA, recB, recC;
            uint4 bufA, bufB, bufC;
            G2_FETCH(A, 0)
            G2_FETCH(B, 1)
            G2_FETCH(C, 2)
            G2_COMP(A, 0)
            if (s0 + 48 < r1) { G2_FETCH(A, 3) }
            if (s0 + 16 < r1) {
                G2_COMP(B, 1)
                if (s0 + 32 < r1) {
                    G2_COMP(C, 2)
                    if (s0 + 48 < r1) {
                        G2_COMP(A, 3)
                    }
                }
            }
        }
        // den reduce over es (equal within quads)
        den += __shfl_xor(den, 4); den += __shfl_xor(den, 8);
        den += __shfl_xor(den, 16); den += __shfl_xor(den, 32);
        // packed num reduce-scatter over es bits {8,4,2} then pair-split
        bool b8 = es & 8, b4 = es & 4, b2 = es & 2;
        f16x2 r4[4];
#pragma unroll
        for (int k = 0; k < 4; ++k) {
            f16x2 send_ = b8 ? num2[k] : num2[k + 4];
            f16x2 recv = i2h(__shfl_xor(h2i(send_), 32));
            r4[k] = (b8 ? num2[k + 4] : num2[k]) + recv;
        }
        f16x2 r2[2];
#pragma unroll
        for (int k = 0; k < 2; ++k) {
            f16x2 send_ = b4 ? r4[k] : r4[k + 2];
            f16x2 recv = i2h(__shfl_xor(h2i(send_), 16));
            r2[k] = (b4 ? r4[k + 2] : r4[k]) + recv;
        }
        f16x2 send1 = b2 ? r2[0] : r2[1];
        f16x2 recv1 = i2h(__shfl_xor(h2i(send1), 8));
        f16x2 r1v = (b2 ? r2[1] : r2[0]) + recv1;
        // sum across es-pair, pick element by es&1 -> channel cb+es
        f16x2 rsum = r1v + i2h(__shfl_xor(h2i(r1v), 4));
        float o = (es & 1) ? (float)rsum[1] : (float)rsum[0];
        o = fmaf(o, 1.f / den, bso);
        // log_softmax over 64 lanes + fc
        float mx = o;
#pragma unroll
        for (int off = 1; off < 64; off <<= 1) mx = fmaxf(mx, __shfl_xor(mx, off));
        float exv = __expf(o - mx);
        float ssum = exv;
#pragma unroll
        for (int off = 1; off < 64; off <<= 1) ssum += __shfl_xor(ssum, off);
        float ls = o - mx - __logf(ssum);
        float contrib = ls * fcwo;
#pragma unroll
        for (int off = 1; off < 64; off <<= 1) contrib += __shfl_xor(contrib, off);
        if (lane == 0) out[n] = contrib + fcb0;
        r0 = r0n; r1 = r1n;
    }
}

extern "C" void kernel_launch(void* const* d_in, const int* in_sizes, int n_in,
                              void* d_out, int out_size, void* d_ws, size_t ws_size,
                              hipStream_t stream) {
    const float* x     = (const float*)d_in[0];
    const int*   ei    = (const int*)d_in[1];
    const float* ew    = (const float*)d_in[2];
    const float* w1l   = (const float*)d_in[3];
    const float* b1l   = (const float*)d_in[4];
    const float* w1r   = (const float*)d_in[5];
    const float* b1r   = (const float*)d_in[6];
    const float* w1e   = (const float*)d_in[7];
    const float* att1  = (const float*)d_in[8];
    const float* bias1 = (const float*)d_in[9];
    const float* w2l   = (const float*)d_in[10];
    const float* b2l   = (const float*)d_in[11];
    const float* w2r   = (const float*)d_in[12];
    const float* b2r   = (const float*)d_in[13];
    const float* w2e   = (const float*)d_in[14];
    const float* att2  = (const float*)d_in[15];
    const float* bias2 = (const float*)d_in[16];
    const float* fcw   = (const float*)d_in[17];
    const float* fcb   = (const float*)d_in[18];
    float* out = (float*)d_out;

    int N = in_sizes[0] / DIN;
    int E = in_sizes[1] / 2;
    int Etot = E + N;
    int NB = (N + BS - 1) >> BSH;   // 196 buckets (<=256)

    char* base = (char*)d_ws;
    size_t off = 0;
    auto alloc = [&](size_t bytes) -> void* {
        void* p = base + off;
        off += (bytes + 15) & ~(size_t)15;
        return p;
    };
    int*      rowptr = (int*)alloc(((size_t)N + 1) * 4);
    unsigned* csr    = (unsigned*)alloc((size_t)Etot * 4);
    int*      h      = (int*)alloc((size_t)NB * NBLK * 4);
    int*      Btot   = (int*)alloc((size_t)NB * 4);
    int*      Boff   = (int*)alloc(((size_t)NB + 1) * 4);
    // region R: [xl8 (N*128) | xr16 (N*128*2)] aliased by barr (E*8 = 12.9 MB <= 19.2 MB);
    // barr dead before k_proj1 writes xl8/xr16 (stream-ordered after k_csr).
    char* R = (char*)alloc((size_t)N * HID * 3);
    int2*          barr = (int2*)R;
    unsigned char* xl8  = (unsigned char*)R;
    __half*        xr16 = (__half*)(R + (size_t)N * HID * 1);
    __half*        h1   = (__half*)alloc((size_t)N * HID * 2);
    __half*        x16  = (__half*)alloc((size_t)N * DIN * 2);
    (void)ws_size;

    // CSR build: deterministic two-level bucket sort (no global atomics)
    k_hist<<<NBLK, 256, 0, stream>>>(ei, h, E, NB);
    k_scancol<<<NB, 256, 0, stream>>>(h, Btot, NB);
    k_scanbuck<<<1, 256, 0, stream>>>(Btot, Boff, rowptr, E, N, NB);
    k_scatter<<<NBLK, 256, 0, stream>>>(ei, ew, h, Boff, barr, E, NB);
    k_csr<<<NB, 512, 0, stream>>>(barr, Boff, rowptr, csr, N, NB);

    // x -> f16
    int tot8 = N * DIN / 8;
    k_x16<<<(tot8 + 255) / 256, 256, 0, stream>>>(x, x16, tot8);

    // full residency: 2048 blocks x 256 thr = 8192 waves
    const int GB = 2048, TB = 256;
    int totWaves = GB * (TB / 64);

    // layer 1
    k_proj1<<<2048, 256, 0, stream>>>(x16, w1l, b1l, w1r, b1r, xl8, xr16, N);
    k_gat1<<<GB, TB, 0, stream>>>(rowptr, csr, xl8, xr16, w1e, att1, bias1, h1, N, totWaves);

    // layer 2 (reuse xl8/xr16 regions; stream-ordered)
    k_proj2<<<2048, 128, 0, stream>>>(h1, w2l, b2l, w2r, b2r, xl8, xr16, N);
    k_gat2<<<GB, TB, 0, stream>>>(rowptr, csr, xl8, xr16, w2e, att2, bias2, fcw, fcb, out, N, totWaves);
}